// Round 1
// baseline (161.349 us; speedup 1.0000x reference)
//
#include <hip/hip_runtime.h>
#include <math.h>

#define BSZ   32
#define SEQL  2048
#define TN    32
#define ENCD  512
#define HIDD  512
#define JW    29            // TN - 3
#define NW    (BSZ * JW)    // 928 windows
#define G4    2048          // 4 * HID

__device__ __forceinline__ float sigm(float x) { return 1.f / (1.f + expf(-x)); }

// ---------------- 1. ragged segment-mean pooling ----------------
// grid = BSZ*TN blocks, 256 threads. block (b,j) averages tokens [start,end].
__global__ __launch_bounds__(256) void pool_k(const float* __restrict__ enc,
                                              const int* __restrict__ end_ids,
                                              float* __restrict__ ts) {
    int blk = blockIdx.x;              // b*TN + j
    int j = blk & 31;
    int b = blk >> 5;
    int e_end   = end_ids[blk];
    int e_start = j ? (end_ids[blk - 1] + 1) : 0;
    int tid = threadIdx.x;
    int col = (tid & 127) << 2;        // float4 column
    int tr  = tid >> 7;                // 0/1: split tokens
    const float* base = enc + (size_t)b * SEQL * ENCD + col;
    float ax = 0.f, ay = 0.f, az = 0.f, aw = 0.f;
    for (int t = e_start + tr; t <= e_end; t += 2) {
        float4 v = *(const float4*)(base + (size_t)t * ENCD);
        ax += v.x; ay += v.y; az += v.z; aw += v.w;
    }
    __shared__ float4 part[128];
    if (tr) part[tid & 127] = make_float4(ax, ay, az, aw);
    __syncthreads();
    if (!tr) {
        float4 o = part[tid];
        float inv = 1.f / (float)(e_end - e_start + 1);
        float4 r = make_float4((ax + o.x) * inv, (ay + o.y) * inv,
                               (az + o.z) * inv, (aw + o.w) * inv);
        *(float4*)(ts + (size_t)blk * ENCD + col) = r;
    }
}

// ---------------- 2. NT GEMM: C[M,2048] = A[M,512] * B[2048,512]^T (+bias) --
// 64x64 tile, BK=16, 256 threads, 4x4 micro-tile per thread.
__global__ __launch_bounds__(256) void gemm_nt(const float* __restrict__ A,
                                               const float* __restrict__ B,
                                               float* __restrict__ C, int M,
                                               const float* __restrict__ bias1,
                                               const float* __restrict__ bias2) {
    const int K = 512, N = 2048;
    __shared__ float As[16][64];
    __shared__ float Bs[16][64];
    int tid = threadIdx.x;
    int m0 = blockIdx.y * 64, n0 = blockIdx.x * 64;
    int tx = tid & 15, ty = tid >> 4;
    int lrow = tid >> 2;               // 0..63
    int lk = (tid & 3) << 2;           // 0,4,8,12
    int am = m0 + lrow; if (am >= M) am = M - 1;   // clamp loads; stores guarded
    const float* Ap = A + (size_t)am * K + lk;
    const float* Bp = B + (size_t)(n0 + lrow) * K + lk;
    float acc[4][4] = {};
    for (int k0 = 0; k0 < K; k0 += 16) {
        float4 av = *(const float4*)(Ap + k0);
        float4 bv = *(const float4*)(Bp + k0);
        __syncthreads();
        As[lk + 0][lrow] = av.x; As[lk + 1][lrow] = av.y;
        As[lk + 2][lrow] = av.z; As[lk + 3][lrow] = av.w;
        Bs[lk + 0][lrow] = bv.x; Bs[lk + 1][lrow] = bv.y;
        Bs[lk + 2][lrow] = bv.z; Bs[lk + 3][lrow] = bv.w;
        __syncthreads();
#pragma unroll
        for (int kk = 0; kk < 16; ++kk) {
            float4 a = *(const float4*)&As[kk][ty << 2];
            float4 b = *(const float4*)&Bs[kk][tx << 2];
            acc[0][0] += a.x * b.x; acc[0][1] += a.x * b.y; acc[0][2] += a.x * b.z; acc[0][3] += a.x * b.w;
            acc[1][0] += a.y * b.x; acc[1][1] += a.y * b.y; acc[1][2] += a.y * b.z; acc[1][3] += a.y * b.w;
            acc[2][0] += a.z * b.x; acc[2][1] += a.z * b.y; acc[2][2] += a.z * b.z; acc[2][3] += a.z * b.w;
            acc[3][0] += a.w * b.x; acc[3][1] += a.w * b.y; acc[3][2] += a.w * b.z; acc[3][3] += a.w * b.w;
        }
    }
    int nb = n0 + (tx << 2);
    float badd[4] = {0.f, 0.f, 0.f, 0.f};
    if (bias1) {
        badd[0] = bias1[nb]; badd[1] = bias1[nb + 1];
        badd[2] = bias1[nb + 2]; badd[3] = bias1[nb + 3];
    }
    if (bias2) {
        badd[0] += bias2[nb]; badd[1] += bias2[nb + 1];
        badd[2] += bias2[nb + 2]; badd[3] += bias2[nb + 3];
    }
#pragma unroll
    for (int i = 0; i < 4; ++i) {
        int m = m0 + (ty << 2) + i;
        if (m < M) {
            float4 r = make_float4(acc[i][0] + badd[0], acc[i][1] + badd[1],
                                   acc[i][2] + badd[2], acc[i][3] + badd[3]);
            *(float4*)(C + (size_t)m * N + nb) = r;
        }
    }
}

// ---------------- 3. LSTM elementwise steps ----------------
// step 1: h=c=0 so gates = XW row of turn (b*TN + j).
__global__ __launch_bounds__(256) void lstm_step1(const float* __restrict__ XW,
                                                  float* __restrict__ H,
                                                  float* __restrict__ Cs) {
    int idx = blockIdx.x * 256 + threadIdx.x;
    if (idx >= NW * HIDD) return;
    int n = idx >> 9, e = idx & 511;
    int b = n / JW, j = n % JW;
    const float* pre = XW + (size_t)(b * TN + j) * G4;
    float gi = pre[e], gf = pre[512 + e], gg = pre[1024 + e], go = pre[1536 + e];
    (void)gf;
    float c = sigm(gi) * tanhf(gg);        // c0 = 0
    float h = sigm(go) * tanhf(c);
    H[idx] = h; Cs[idx] = c;
}

// steps 2,3: gates = XW row of turn (b*TN + j + t) + G row n (= h_prev @ W_hh^T)
__global__ __launch_bounds__(256) void lstm_step(const float* __restrict__ XW,
                                                 const float* __restrict__ G,
                                                 float* __restrict__ H,
                                                 float* __restrict__ Cs, int t) {
    int idx = blockIdx.x * 256 + threadIdx.x;
    if (idx >= NW * HIDD) return;
    int n = idx >> 9, e = idx & 511;
    int b = n / JW, j = n % JW;
    const float* px = XW + (size_t)(b * TN + j + t) * G4;
    const float* pg = G + (size_t)n * G4;
    float gi = px[e]        + pg[e];
    float gf = px[512 + e]  + pg[512 + e];
    float gg = px[1024 + e] + pg[1024 + e];
    float go = px[1536 + e] + pg[1536 + e];
    float c = Cs[idx];
    float cn = sigm(gf) * c + sigm(gi) * tanhf(gg);
    float h = sigm(go) * tanhf(cn);
    H[idx] = h; Cs[idx] = cn;
}

// ---------------- 4. scores: one wave per row ----------------
// rows 0..927: sscore = dot(hT[n], fc_w[0:512]); rows 928..1951: tscore.
__global__ __launch_bounds__(256) void scores_k(const float* __restrict__ hT,
                                                const float* __restrict__ ts,
                                                const float* __restrict__ fcw,
                                                float* __restrict__ ss,
                                                float* __restrict__ tsc) {
    int row = blockIdx.x * 4 + (threadIdx.x >> 6);
    int lane = threadIdx.x & 63;
    if (row >= NW + BSZ * TN) return;
    const float *x, *w;
    if (row < NW) { x = hT + (size_t)row * HIDD; w = fcw; }
    else          { x = ts + (size_t)(row - NW) * ENCD; w = fcw + HIDD; }
    float acc = 0.f;
#pragma unroll
    for (int it = 0; it < 2; ++it) {
        int k = (lane << 2) + it * 256;
        float4 xv = *(const float4*)(x + k);
        float4 wv = *(const float4*)(w + k);
        acc += xv.x * wv.x + xv.y * wv.y + xv.z * wv.z + xv.w * wv.w;
    }
#pragma unroll
    for (int s = 32; s; s >>= 1) acc += __shfl_down(acc, s, 64);
    if (lane == 0) {
        if (row < NW) ss[row] = acc;
        else tsc[row - NW] = acc;
    }
}

// ---------------- 5. loss: one block ----------------
__global__ __launch_bounds__(1024) void loss_k(const float* __restrict__ ss,
                                               const float* __restrict__ tsc,
                                               const float* __restrict__ fcb,
                                               float* __restrict__ out) {
    int tid = threadIdx.x;
    float l = 0.f;
    if (tid < NW) {
        int b = tid / JW, j = tid % JW;
        float base = ss[tid] + fcb[0];
        int nv = JW - j;                 // valid candidates: k in [0, nv)
        float l0 = 0.f, m = -1e30f;
        for (int k = 0; k < nv; ++k) {
            float lg = base + tsc[b * TN + j + 3 + k];
            if (k == 0) l0 = lg;
            m = fmaxf(m, lg);
        }
        float sum = 0.f;
        for (int k = 0; k < nv; ++k) {
            float lg = base + tsc[b * TN + j + 3 + k];
            sum += expf(lg - m);
        }
        l = (m + logf(sum)) - l0;
    }
    // block reduce
    __shared__ float red[16];
#pragma unroll
    for (int s = 32; s; s >>= 1) l += __shfl_down(l, s, 64);
    int wid = tid >> 6, lane = tid & 63;
    if (lane == 0) red[wid] = l;
    __syncthreads();
    if (tid == 0) {
        float tot = 0.f;
        for (int i = 0; i < 16; ++i) tot += red[i];
        out[0] = tot / (float)NW;
    }
}

extern "C" void kernel_launch(void* const* d_in, const int* in_sizes, int n_in,
                              void* d_out, int out_size, void* d_ws, size_t ws_size,
                              hipStream_t stream) {
    const float* enc     = (const float*)d_in[0];
    const int*   end_ids = (const int*)d_in[1];
    const float* W_ih    = (const float*)d_in[2];
    const float* W_hh    = (const float*)d_in[3];
    const float* b_ih    = (const float*)d_in[4];
    const float* b_hh    = (const float*)d_in[5];
    const float* fc_w    = (const float*)d_in[6];
    const float* fc_b    = (const float*)d_in[7];
    float* out = (float*)d_out;

    float* ws = (float*)d_ws;
    // workspace layout (floats)
    float* ts  = ws;                            // 1024*512   = 524288
    float* XW  = ts + 1024 * 512;               // 1024*2048  = 2097152
    float* H   = XW + 1024 * 2048;              // 960*512 (pad to 15 blocks)
    float* Cs  = H + 960 * 512;
    float* G   = Cs + 960 * 512;                // 960*2048
    float* ss  = G + 960 * 2048;                // 928
    float* tsc = ss + 1024;                     // 1024

    // 1. pooling -> turn_states [1024, 512]
    pool_k<<<BSZ * TN, 256, 0, stream>>>(enc, end_ids, ts);
    // 2. XW = ts @ W_ih^T + (b_ih + b_hh)  [1024, 2048]
    gemm_nt<<<dim3(32, 16), 256, 0, stream>>>(ts, W_ih, XW, 1024, b_ih, b_hh);
    // 3. LSTM step 1 (h=c=0)
    lstm_step1<<<(NW * HIDD) / 256, 256, 0, stream>>>(XW, H, Cs);
    // 4. step 2: G = H @ W_hh^T ; elementwise
    gemm_nt<<<dim3(32, 15), 256, 0, stream>>>(H, W_hh, G, NW, nullptr, nullptr);
    lstm_step<<<(NW * HIDD) / 256, 256, 0, stream>>>(XW, G, H, Cs, 1);
    // 5. step 3
    gemm_nt<<<dim3(32, 15), 256, 0, stream>>>(H, W_hh, G, NW, nullptr, nullptr);
    lstm_step<<<(NW * HIDD) / 256, 256, 0, stream>>>(XW, G, H, Cs, 2);
    // 6. scores
    scores_k<<<(NW + BSZ * TN + 3) / 4, 256, 0, stream>>>(H, ts, fc_w, ss, tsc);
    // 7. loss -> scalar
    loss_k<<<1, 1024, 0, stream>>>(ss, tsc, fc_b, out);
}

// Round 2
// 83.695 us; speedup vs baseline: 1.9278x; 1.9278x over previous
//
#include <hip/hip_runtime.h>
#include <math.h>

#define BSZ   32
#define SEQL  2048
#define TN    32
#define ENCD  512
#define HIDD  512
#define JW    29            // TN - 3
#define NW    (BSZ * JW)    // 928 windows
#define G4    2048          // 4 * HID

typedef short bf16x8 __attribute__((ext_vector_type(8)));
typedef float f32x4  __attribute__((ext_vector_type(4)));

__device__ __forceinline__ float sigm(float x) { return 1.f / (1.f + expf(-x)); }

__device__ __forceinline__ unsigned short f2bf(float x) {
    union { float f; unsigned u; } v; v.f = x;
    unsigned u = v.u;
    u += 0x7FFF + ((u >> 16) & 1);          // RNE
    return (unsigned short)(u >> 16);
}

#define GLOAD_LDS16(gp, lp)                                                    \
    __builtin_amdgcn_global_load_lds(                                          \
        (const __attribute__((address_space(1))) void*)(gp),                   \
        (__attribute__((address_space(3))) void*)(lp), 16, 0, 0)

// ---------------- 0. weight f32 -> bf16 conversion ----------------
__global__ __launch_bounds__(256) void convw_k(const float* __restrict__ w1,
                                               const float* __restrict__ w2,
                                               short* __restrict__ o1,
                                               short* __restrict__ o2) {
    int idx = blockIdx.x * 256 + threadIdx.x;      // 262144 total
    int t = idx >> 17;                             // tensor select (131072 each)
    int i = idx & 131071;
    const float* s = (t ? w2 : w1) + (size_t)i * 8;
    short* o = (t ? o2 : o1) + (size_t)i * 8;
    float4 a = ((const float4*)s)[0];
    float4 b = ((const float4*)s)[1];
    union { short v[8]; bf16x8 p; } r;
    r.v[0] = (short)f2bf(a.x); r.v[1] = (short)f2bf(a.y);
    r.v[2] = (short)f2bf(a.z); r.v[3] = (short)f2bf(a.w);
    r.v[4] = (short)f2bf(b.x); r.v[5] = (short)f2bf(b.y);
    r.v[6] = (short)f2bf(b.z); r.v[7] = (short)f2bf(b.w);
    *(bf16x8*)o = r.p;
}

// ---------------- 1. ragged segment-mean pooling ----------------
__global__ __launch_bounds__(256) void pool_k(const float* __restrict__ enc,
                                              const int* __restrict__ end_ids,
                                              float* __restrict__ ts,
                                              short* __restrict__ tsbf) {
    int blk = blockIdx.x;              // b*TN + j
    int j = blk & 31;
    int b = blk >> 5;
    int e_end   = end_ids[blk];
    int e_start = j ? (end_ids[blk - 1] + 1) : 0;
    int tid = threadIdx.x;
    int col = (tid & 127) << 2;
    int tr  = tid >> 7;
    const float* base = enc + (size_t)b * SEQL * ENCD + col;
    float ax = 0.f, ay = 0.f, az = 0.f, aw = 0.f;
    for (int t = e_start + tr; t <= e_end; t += 2) {
        float4 v = *(const float4*)(base + (size_t)t * ENCD);
        ax += v.x; ay += v.y; az += v.z; aw += v.w;
    }
    __shared__ float4 part[128];
    if (tr) part[tid & 127] = make_float4(ax, ay, az, aw);
    __syncthreads();
    if (!tr) {
        float4 o = part[tid];
        float inv = 1.f / (float)(e_end - e_start + 1);
        float4 r = make_float4((ax + o.x) * inv, (ay + o.y) * inv,
                               (az + o.z) * inv, (aw + o.w) * inv);
        *(float4*)(ts + (size_t)blk * ENCD + col) = r;
        union { unsigned short v[4]; uint2 p; } q;
        q.v[0] = f2bf(r.x); q.v[1] = f2bf(r.y);
        q.v[2] = f2bf(r.z); q.v[3] = f2bf(r.w);
        *(uint2*)(tsbf + (size_t)blk * ENCD + col) = q.p;
    }
}

// ---------------- 2. bf16 MFMA GEMM: C[1024,2048] = A[1024,512] B[2048,512]^T
// BM=64 BN=128 BK=64, 512 threads (8 waves 2x4), frag 2x2 of 16x16x32.
__global__ __launch_bounds__(512) void gemm_mfma(const short* __restrict__ A,
                                                 const short* __restrict__ B,
                                                 float* __restrict__ C,
                                                 const float* __restrict__ bias1,
                                                 const float* __restrict__ bias2) {
    __shared__ short Als[64 * 64];     // 8 KB
    __shared__ short Bls[128 * 64];    // 16 KB
    int tid = threadIdx.x, w = tid >> 6, lane = tid & 63;
    int m0 = blockIdx.y * 64, n0 = blockIdx.x * 128;
    int mw = (w >> 2) * 32, nw = (w & 3) * 32;
    int l15 = lane & 15, l4 = lane >> 4;
    f32x4 acc[2][2] = {};

    for (int k0 = 0; k0 < 512; k0 += 64) {
        // stage: 24 KB = 24 wave-chunks of 1024 B; wave w takes chunks w*3..w*3+2.
#pragma unroll
        for (int i = 0; i < 3; ++i) {
            int c = w * 3 + i;
            if (c < 8) {                               // A tile: 8 chunks
                int unit = c * 64 + lane;              // 16B unit
                int row = unit >> 3, slot = unit & 7;
                int scol = slot ^ (row & 7);           // pre-swizzled source
                const short* gp = A + (size_t)(m0 + row) * 512 + k0 + scol * 8;
                GLOAD_LDS16(gp, &Als[c * 512]);
            } else {                                   // B tile: 16 chunks
                int unit = (c - 8) * 64 + lane;
                int row = unit >> 3, slot = unit & 7;
                int scol = slot ^ (row & 7);
                const short* gp = B + (size_t)(n0 + row) * 512 + k0 + scol * 8;
                GLOAD_LDS16(gp, &Bls[(c - 8) * 512]);
            }
        }
        __syncthreads();                               // drains vmcnt + barrier

        bf16x8 af[2][2], bfr[2][2];
#pragma unroll
        for (int kk = 0; kk < 2; ++kk) {
#pragma unroll
            for (int fm = 0; fm < 2; ++fm) {
                int row = mw + fm * 16 + l15;
                int s = (kk * 4 + l4) ^ (row & 7);
                af[fm][kk] = *(const bf16x8*)&Als[row * 64 + s * 8];
            }
#pragma unroll
            for (int fn = 0; fn < 2; ++fn) {
                int row = nw + fn * 16 + l15;
                int s = (kk * 4 + l4) ^ (row & 7);
                bfr[fn][kk] = *(const bf16x8*)&Bls[row * 64 + s * 8];
            }
        }
#pragma unroll
        for (int kk = 0; kk < 2; ++kk)
#pragma unroll
            for (int fm = 0; fm < 2; ++fm)
#pragma unroll
                for (int fn = 0; fn < 2; ++fn)
                    acc[fm][fn] = __builtin_amdgcn_mfma_f32_16x16x32_bf16(
                        af[fm][kk], bfr[fn][kk], acc[fm][fn], 0, 0, 0);
        __syncthreads();
    }

#pragma unroll
    for (int fn = 0; fn < 2; ++fn) {
        int n = n0 + nw + fn * 16 + l15;
        float badd = 0.f;
        if (bias1) badd += bias1[n];
        if (bias2) badd += bias2[n];
#pragma unroll
        for (int fm = 0; fm < 2; ++fm) {
            int mb = m0 + mw + fm * 16 + l4 * 4;
#pragma unroll
            for (int r = 0; r < 4; ++r)
                C[(size_t)(mb + r) * 2048 + n] = acc[fm][fn][r] + badd;
        }
    }
}

// ---------------- 3. LSTM elementwise steps ----------------
__global__ __launch_bounds__(256) void lstm_step1(const float* __restrict__ XW,
                                                  float* __restrict__ H,
                                                  short* __restrict__ Hbf,
                                                  float* __restrict__ Cs) {
    int idx = blockIdx.x * 256 + threadIdx.x;
    if (idx >= NW * HIDD) return;
    int n = idx >> 9, e = idx & 511;
    int b = n / JW, j = n % JW;
    const float* pre = XW + (size_t)(b * TN + j) * G4;
    float gi = pre[e], gg = pre[1024 + e], go = pre[1536 + e];
    float c = sigm(gi) * tanhf(gg);
    float h = sigm(go) * tanhf(c);
    H[idx] = h; Hbf[idx] = (short)f2bf(h); Cs[idx] = c;
}

__global__ __launch_bounds__(256) void lstm_step(const float* __restrict__ XW,
                                                 const float* __restrict__ G,
                                                 float* __restrict__ H,
                                                 short* __restrict__ Hbf,
                                                 float* __restrict__ Cs, int t) {
    int idx = blockIdx.x * 256 + threadIdx.x;
    if (idx >= NW * HIDD) return;
    int n = idx >> 9, e = idx & 511;
    int b = n / JW, j = n % JW;
    const float* px = XW + (size_t)(b * TN + j + t) * G4;
    const float* pg = G + (size_t)n * G4;
    float gi = px[e]        + pg[e];
    float gf = px[512 + e]  + pg[512 + e];
    float gg = px[1024 + e] + pg[1024 + e];
    float go = px[1536 + e] + pg[1536 + e];
    float c = Cs[idx];
    float cn = sigm(gf) * c + sigm(gi) * tanhf(gg);
    float h = sigm(go) * tanhf(cn);
    H[idx] = h; Hbf[idx] = (short)f2bf(h); Cs[idx] = cn;
}

// ---------------- 4. scores ----------------
__global__ __launch_bounds__(256) void scores_k(const float* __restrict__ hT,
                                                const float* __restrict__ ts,
                                                const float* __restrict__ fcw,
                                                float* __restrict__ ss,
                                                float* __restrict__ tsc) {
    int row = blockIdx.x * 4 + (threadIdx.x >> 6);
    int lane = threadIdx.x & 63;
    if (row >= NW + BSZ * TN) return;
    const float *x, *w;
    if (row < NW) { x = hT + (size_t)row * HIDD; w = fcw; }
    else          { x = ts + (size_t)(row - NW) * ENCD; w = fcw + HIDD; }
    float acc = 0.f;
#pragma unroll
    for (int it = 0; it < 2; ++it) {
        int k = (lane << 2) + it * 256;
        float4 xv = *(const float4*)(x + k);
        float4 wv = *(const float4*)(w + k);
        acc += xv.x * wv.x + xv.y * wv.y + xv.z * wv.z + xv.w * wv.w;
    }
#pragma unroll
    for (int s = 32; s; s >>= 1) acc += __shfl_down(acc, s, 64);
    if (lane == 0) {
        if (row < NW) ss[row] = acc;
        else tsc[row - NW] = acc;
    }
}

// ---------------- 5. loss ----------------
__global__ __launch_bounds__(1024) void loss_k(const float* __restrict__ ss,
                                               const float* __restrict__ tsc,
                                               const float* __restrict__ fcb,
                                               float* __restrict__ out) {
    int tid = threadIdx.x;
    float l = 0.f;
    if (tid < NW) {
        int b = tid / JW, j = tid % JW;
        float base = ss[tid] + fcb[0];
        int nv = JW - j;
        float l0 = 0.f, m = -1e30f;
        for (int k = 0; k < nv; ++k) {
            float lg = base + tsc[b * TN + j + 3 + k];
            if (k == 0) l0 = lg;
            m = fmaxf(m, lg);
        }
        float sum = 0.f;
        for (int k = 0; k < nv; ++k) {
            float lg = base + tsc[b * TN + j + 3 + k];
            sum += expf(lg - m);
        }
        l = (m + logf(sum)) - l0;
    }
    __shared__ float red[16];
#pragma unroll
    for (int s = 32; s; s >>= 1) l += __shfl_down(l, s, 64);
    int wid = tid >> 6, lane = tid & 63;
    if (lane == 0) red[wid] = l;
    __syncthreads();
    if (tid == 0) {
        float tot = 0.f;
        for (int i = 0; i < 16; ++i) tot += red[i];
        out[0] = tot / (float)NW;
    }
}

extern "C" void kernel_launch(void* const* d_in, const int* in_sizes, int n_in,
                              void* d_out, int out_size, void* d_ws, size_t ws_size,
                              hipStream_t stream) {
    const float* enc     = (const float*)d_in[0];
    const int*   end_ids = (const int*)d_in[1];
    const float* W_ih    = (const float*)d_in[2];
    const float* W_hh    = (const float*)d_in[3];
    const float* b_ih    = (const float*)d_in[4];
    const float* b_hh    = (const float*)d_in[5];
    const float* fc_w    = (const float*)d_in[6];
    const float* fc_b    = (const float*)d_in[7];
    float* out = (float*)d_out;

    float* ws = (float*)d_ws;
    float* ts  = ws;                       // 1024*512
    float* XW  = ts + 1024 * 512;          // 1024*2048
    float* H   = XW + 1024 * 2048;         // 1024*512 (pad rows 928..1023)
    float* Cs  = H + 1024 * 512;           // 1024*512
    float* G   = Cs + 1024 * 512;          // 1024*2048
    float* ss  = G + 1024 * 2048;          // 1024
    float* tsc = ss + 1024;                // 1024
    short* tsbf   = (short*)(tsc + 1024);  // 1024*512
    short* Wih_bf = tsbf + 1024 * 512;     // 2048*512
    short* Whh_bf = Wih_bf + 2048 * 512;   // 2048*512
    short* Hbf    = Whh_bf + 2048 * 512;   // 1024*512 (rows >=928 are poison, finite)

    // 0. weights -> bf16
    convw_k<<<1024, 256, 0, stream>>>(W_ih, W_hh, Wih_bf, Whh_bf);
    // 1. pooling -> ts (f32) + tsbf (bf16)
    pool_k<<<BSZ * TN, 256, 0, stream>>>(enc, end_ids, ts, tsbf);
    // 2. XW = ts @ W_ih^T + (b_ih + b_hh)
    gemm_mfma<<<dim3(16, 16), 512, 0, stream>>>(tsbf, Wih_bf, XW, b_ih, b_hh);
    // 3. LSTM step 1 (h=c=0)
    lstm_step1<<<(NW * HIDD) / 256, 256, 0, stream>>>(XW, H, Hbf, Cs);
    // 4. step 2
    gemm_mfma<<<dim3(16, 16), 512, 0, stream>>>(Hbf, Whh_bf, G, nullptr, nullptr);
    lstm_step<<<(NW * HIDD) / 256, 256, 0, stream>>>(XW, G, H, Hbf, Cs, 1);
    // 5. step 3
    gemm_mfma<<<dim3(16, 16), 512, 0, stream>>>(Hbf, Whh_bf, G, nullptr, nullptr);
    lstm_step<<<(NW * HIDD) / 256, 256, 0, stream>>>(XW, G, H, Hbf, Cs, 2);
    // 6. scores
    scores_k<<<(NW + BSZ * TN + 3) / 4, 256, 0, stream>>>(H, ts, fc_w, ss, tsc);
    // 7. loss
    loss_k<<<1, 1024, 0, stream>>>(ss, tsc, fc_b, out);
}

// Round 3
// 73.091 us; speedup vs baseline: 2.2075x; 1.1451x over previous
//
#include <hip/hip_runtime.h>
#include <math.h>

#define BSZ   32
#define SEQL  2048
#define TN    32
#define ENCD  512
#define HIDD  512
#define JW    29            // TN - 3
#define NW    (BSZ * JW)    // 928 windows

typedef short bf16x8 __attribute__((ext_vector_type(8)));
typedef float f32x4  __attribute__((ext_vector_type(4)));

__device__ __forceinline__ float sigm(float x) { return 1.f / (1.f + expf(-x)); }

__device__ __forceinline__ unsigned short f2bf(float x) {
    union { float f; unsigned u; } v; v.f = x;
    unsigned u = v.u;
    u += 0x7FFF + ((u >> 16) & 1);          // RNE
    return (unsigned short)(u >> 16);
}
__device__ __forceinline__ float bf2f(short s) {
    union { unsigned u; float f; } v; v.u = ((unsigned)(unsigned short)s) << 16;
    return v.f;
}

#define GLOAD_LDS16(gp, lp)                                                    \
    __builtin_amdgcn_global_load_lds(                                          \
        (const __attribute__((address_space(1))) void*)(gp),                   \
        (__attribute__((address_space(3))) void*)(lp), 16, 0, 0)

// ---------------- 1. pooling (blocks 0..1023) + weight conv (1024..2047) ----
__global__ __launch_bounds__(256) void prep_k(const float* __restrict__ enc,
                                              const int* __restrict__ end_ids,
                                              short* __restrict__ tsbf,
                                              const float* __restrict__ w1,
                                              const float* __restrict__ w2,
                                              short* __restrict__ o1,
                                              short* __restrict__ o2) {
    int tid = threadIdx.x;
    if (blockIdx.x >= 1024) {
        // ---- bf16 weight conversion: 2x (2048x512)
        int idx = (blockIdx.x - 1024) * 256 + tid;      // 262144 total
        int t = idx >> 17;
        int i = idx & 131071;
        const float* s = (t ? w2 : w1) + (size_t)i * 8;
        short* o = (t ? o2 : o1) + (size_t)i * 8;
        float4 a = ((const float4*)s)[0];
        float4 b = ((const float4*)s)[1];
        union { short v[8]; bf16x8 p; } r;
        r.v[0] = (short)f2bf(a.x); r.v[1] = (short)f2bf(a.y);
        r.v[2] = (short)f2bf(a.z); r.v[3] = (short)f2bf(a.w);
        r.v[4] = (short)f2bf(b.x); r.v[5] = (short)f2bf(b.y);
        r.v[6] = (short)f2bf(b.z); r.v[7] = (short)f2bf(b.w);
        *(bf16x8*)o = r.p;
        return;
    }
    // ---- ragged segment-mean pooling, block = turn (b*TN + j)
    int blk = blockIdx.x;
    int j = blk & 31;
    int b = blk >> 5;
    int e_end   = end_ids[blk];
    int e_start = j ? (end_ids[blk - 1] + 1) : 0;
    int col = (tid & 127) << 2;
    int tr  = tid >> 7;
    const float* base = enc + (size_t)b * SEQL * ENCD + col;
    float ax = 0.f, ay = 0.f, az = 0.f, aw = 0.f;
    for (int t = e_start + tr; t <= e_end; t += 2) {
        float4 v = *(const float4*)(base + (size_t)t * ENCD);
        ax += v.x; ay += v.y; az += v.z; aw += v.w;
    }
    __shared__ float4 part[128];
    if (tr) part[tid & 127] = make_float4(ax, ay, az, aw);
    __syncthreads();
    if (!tr) {
        float4 o = part[tid];
        float inv = 1.f / (float)(e_end - e_start + 1);
        union { unsigned short v[4]; uint2 p; } q;
        q.v[0] = f2bf((ax + o.x) * inv); q.v[1] = f2bf((ay + o.y) * inv);
        q.v[2] = f2bf((az + o.z) * inv); q.v[3] = f2bf((aw + o.w) * inv);
        *(uint2*)(tsbf + (size_t)blk * ENCD + col) = q.p;
    }
}

// ---------------- 2. fused GEMM + LSTM step ----------------
// A [1024,512] bf16 (turn rows), B [2048,512] bf16 (rows = gate*512 + hcol).
// Block: BM=64 rows x 32 h-cols (x4 gates = 128 MFMA cols). 4 waves (2m x 2h),
// wave frag acc[fm 2][gate 4]. Double-buffered LDS staging via global_load_lds
// with XOR-swizzled source (rule #21); read with matching XOR.
// Epilogue: in-register LSTM gate math.
//   STEP 1: gates = acc + (b_ih+b_hh); write XW (f32); c=sig(i)tanh(g);
//           h=sig(o)tanh(c); write Cb, Hout(bf16).
//   STEP 2/3: gates = acc + XW[row+STEP-1]; c'=sig(f)Cb+sig(i)tanh(g); ...
template <int STEP>
__global__ __launch_bounds__(256) void gemm_lstm(const short* __restrict__ A,
                                                 const short* __restrict__ B,
                                                 float* __restrict__ XW,
                                                 float* __restrict__ Cb,
                                                 short* __restrict__ Hout,
                                                 const float* __restrict__ b_ih,
                                                 const float* __restrict__ b_hh) {
    __shared__ short Als[2][8 * 512];      // 2 x 8 KB
    __shared__ short Bls[2][16 * 512];     // 2 x 16 KB
    int tid = threadIdx.x, w = tid >> 6, lane = tid & 63;
    int l15 = lane & 15, l4 = lane >> 4;
    int m0 = blockIdx.y * 64;
    int hcol0 = blockIdx.x * 32;
    int wm = (w >> 1) * 32, wh = (w & 1) * 16;
    const short* Aptr = A + (size_t)m0 * 512;
    f32x4 acc[2][4] = {};

    auto stage = [&](int sel, int k0) {
#pragma unroll
        for (int i = 0; i < 6; ++i) {
            int c = w * 6 + i;
            if (c < 8) {                               // A: 8 chunks of 1 KB
                int unit = c * 64 + lane;
                int row = unit >> 3, slot = unit & 7;
                int scol = slot ^ (row & 7);
                GLOAD_LDS16(Aptr + (size_t)row * 512 + k0 + scol * 8,
                            &Als[sel][c * 512]);
            } else {                                   // B: 16 chunks
                int cc = c - 8;
                int unit = cc * 64 + lane;
                int rr = unit >> 3, slot = unit & 7;
                int grow = (rr >> 5) * 512 + hcol0 + (rr & 31);
                int scol = slot ^ (rr & 7);
                GLOAD_LDS16(B + (size_t)grow * 512 + k0 + scol * 8,
                            &Bls[sel][cc * 512]);
            }
        }
    };

    stage(0, 0);
    __syncthreads();                       // drains vmcnt before barrier
    int sel = 0;
    for (int t = 0; t < 8; ++t) {
        if (t < 7) stage(sel ^ 1, (t + 1) * 64);
        bf16x8 af[2][2], bfr[4][2];
#pragma unroll
        for (int kk = 0; kk < 2; ++kk) {
#pragma unroll
            for (int fm = 0; fm < 2; ++fm) {
                int row = wm + fm * 16 + l15;
                int s = (kk * 4 + l4) ^ (row & 7);
                af[fm][kk] = *(const bf16x8*)&Als[sel][row * 64 + s * 8];
            }
#pragma unroll
            for (int g = 0; g < 4; ++g) {
                int rr = g * 32 + wh + l15;
                int s = (kk * 4 + l4) ^ (rr & 7);
                bfr[g][kk] = *(const bf16x8*)&Bls[sel][rr * 64 + s * 8];
            }
        }
#pragma unroll
        for (int kk = 0; kk < 2; ++kk)
#pragma unroll
            for (int fm = 0; fm < 2; ++fm)
#pragma unroll
                for (int g = 0; g < 4; ++g)
                    acc[fm][g] = __builtin_amdgcn_mfma_f32_16x16x32_bf16(
                        af[fm][kk], bfr[g][kk], acc[fm][g], 0, 0, 0);
        __syncthreads();
        sel ^= 1;
    }

    // ---- epilogue: in-register LSTM
    int hcol = hcol0 + wh + l15;
    float b0 = 0.f, b1 = 0.f, b2 = 0.f, b3 = 0.f;
    if (STEP == 1) {
        b0 = b_ih[hcol]        + b_hh[hcol];
        b1 = b_ih[512 + hcol]  + b_hh[512 + hcol];
        b2 = b_ih[1024 + hcol] + b_hh[1024 + hcol];
        b3 = b_ih[1536 + hcol] + b_hh[1536 + hcol];
    }
#pragma unroll
    for (int fm = 0; fm < 2; ++fm) {
        int rbase = m0 + wm + fm * 16 + l4 * 4;
#pragma unroll
        for (int r = 0; r < 4; ++r) {
            int row = rbase + r;
            float gi = acc[fm][0][r], gf = acc[fm][1][r];
            float gg = acc[fm][2][r], go = acc[fm][3][r];
            float cn;
            if (STEP == 1) {
                gi += b0; gf += b1; gg += b2; go += b3;
                float* xp = XW + (size_t)row * 2048 + hcol;
                xp[0] = gi; xp[512] = gf; xp[1024] = gg; xp[1536] = go;
                cn = sigm(gi) * tanhf(gg);           // c0 = 0
            } else {
                int xr = row + (STEP - 1); if (xr > 1023) xr = 1023;
                const float* xp = XW + (size_t)xr * 2048 + hcol;
                gi += xp[0]; gf += xp[512]; gg += xp[1024]; go += xp[1536];
                float cprev = Cb[(size_t)row * 512 + hcol];
                cn = sigm(gf) * cprev + sigm(gi) * tanhf(gg);
            }
            float h = sigm(go) * tanhf(cn);
            if (STEP < 3) Cb[(size_t)row * 512 + hcol] = cn;
            Hout[(size_t)row * 512 + hcol] = (short)f2bf(h);
        }
    }
}

// ---------------- 3. scores: one wave per row ----------------
// rows 0..927: sscore over H3 (turn-indexed); rows 928..1951: tscore over tsbf.
__global__ __launch_bounds__(256) void scores_k(const short* __restrict__ h3,
                                                const short* __restrict__ tsbf,
                                                const float* __restrict__ fcw,
                                                float* __restrict__ ss,
                                                float* __restrict__ tsc) {
    int row = blockIdx.x * 4 + (threadIdx.x >> 6);
    int lane = threadIdx.x & 63;
    if (row >= NW + BSZ * TN) return;
    const short* x;
    const float* wv;
    if (row < NW) {
        int turn = (row / JW) * TN + (row % JW);
        x = h3 + (size_t)turn * HIDD; wv = fcw;
    } else {
        x = tsbf + (size_t)(row - NW) * ENCD; wv = fcw + HIDD;
    }
    int k = lane << 3;
    bf16x8 xv = *(const bf16x8*)(x + k);
    float4 w0 = *(const float4*)(wv + k);
    float4 w1 = *(const float4*)(wv + k + 4);
    float acc = bf2f(xv[0]) * w0.x + bf2f(xv[1]) * w0.y +
                bf2f(xv[2]) * w0.z + bf2f(xv[3]) * w0.w +
                bf2f(xv[4]) * w1.x + bf2f(xv[5]) * w1.y +
                bf2f(xv[6]) * w1.z + bf2f(xv[7]) * w1.w;
#pragma unroll
    for (int s = 32; s; s >>= 1) acc += __shfl_down(acc, s, 64);
    if (lane == 0) {
        if (row < NW) ss[row] = acc;
        else tsc[row - NW] = acc;
    }
}

// ---------------- 4. loss: one block ----------------
__global__ __launch_bounds__(1024) void loss_k(const float* __restrict__ ss,
                                               const float* __restrict__ tsc,
                                               const float* __restrict__ fcb,
                                               float* __restrict__ out) {
    int tid = threadIdx.x;
    float l = 0.f;
    if (tid < NW) {
        int b = tid / JW, j = tid % JW;
        float base = ss[tid] + fcb[0];
        int nv = JW - j;
        float l0 = 0.f, m = -1e30f;
        for (int k = 0; k < nv; ++k) {
            float lg = base + tsc[b * TN + j + 3 + k];
            if (k == 0) l0 = lg;
            m = fmaxf(m, lg);
        }
        float sum = 0.f;
        for (int k = 0; k < nv; ++k) {
            float lg = base + tsc[b * TN + j + 3 + k];
            sum += expf(lg - m);
        }
        l = (m + logf(sum)) - l0;
    }
    __shared__ float red[16];
#pragma unroll
    for (int s = 32; s; s >>= 1) l += __shfl_down(l, s, 64);
    int wid = tid >> 6, lane = tid & 63;
    if (lane == 0) red[wid] = l;
    __syncthreads();
    if (tid == 0) {
        float tot = 0.f;
        for (int i = 0; i < 16; ++i) tot += red[i];
        out[0] = tot / (float)NW;
    }
}

extern "C" void kernel_launch(void* const* d_in, const int* in_sizes, int n_in,
                              void* d_out, int out_size, void* d_ws, size_t ws_size,
                              hipStream_t stream) {
    const float* enc     = (const float*)d_in[0];
    const int*   end_ids = (const int*)d_in[1];
    const float* W_ih    = (const float*)d_in[2];
    const float* W_hh    = (const float*)d_in[3];
    const float* b_ih    = (const float*)d_in[4];
    const float* b_hh    = (const float*)d_in[5];
    const float* fc_w    = (const float*)d_in[6];
    const float* fc_b    = (const float*)d_in[7];
    float* out = (float*)d_out;

    float* ws = (float*)d_ws;
    float* XW  = ws;                        // 1024*2048 f32
    float* Cb  = XW + 1024 * 2048;          // 1024*512 f32
    float* ss  = Cb + 1024 * 512;           // 1024
    float* tsc = ss + 1024;                 // 1024
    short* tsbf   = (short*)(tsc + 1024);   // 1024*512 bf16
    short* Wih_bf = tsbf + 1024 * 512;      // 2048*512
    short* Whh_bf = Wih_bf + 2048 * 512;    // 2048*512
    short* HA     = Whh_bf + 2048 * 512;    // 1024*512
    short* HB     = HA + 1024 * 512;        // 1024*512

    // 1. pooling -> tsbf; weights -> bf16
    prep_k<<<2048, 256, 0, stream>>>(enc, end_ids, tsbf, W_ih, W_hh, Wih_bf, Whh_bf);
    // 2. step 1: XW = ts @ Wih^T + bias (saved); h1,c1 in epilogue
    gemm_lstm<1><<<dim3(16, 16), 256, 0, stream>>>(tsbf, Wih_bf, XW, Cb, HA, b_ih, b_hh);
    // 3. step 2: gates = h1 @ Whh^T + XW[r+1]
    gemm_lstm<2><<<dim3(16, 16), 256, 0, stream>>>(HA, Whh_bf, XW, Cb, HB, b_ih, b_hh);
    // 4. step 3: gates = h2 @ Whh^T + XW[r+2]
    gemm_lstm<3><<<dim3(16, 16), 256, 0, stream>>>(HB, Whh_bf, XW, Cb, HA, b_ih, b_hh);
    // 5. scores
    scores_k<<<(NW + BSZ * TN + 3) / 4, 256, 0, stream>>>(HA, tsbf, fc_w, ss, tsc);
    // 6. loss
    loss_k<<<1, 1024, 0, stream>>>(ss, tsc, fc_b, out);
}